// Round 5
// baseline (20933.192 us; speedup 1.0000x reference)
//
#include <hip/hip_runtime.h>
#include <stdint.h>

#define TB 8192
#define NBATCH 2
#define RES_C 512
#define SKIP_C 256
#define MEL_C 80
#define NLAYERS 30
#define XSTRIDE 9216   // TB + 2*512 zero-pad rows per batch (dilation guard)

typedef short v8s __attribute__((ext_vector_type(8)));
typedef float v4f __attribute__((ext_vector_type(4)));
typedef unsigned short v4u16 __attribute__((ext_vector_type(4)));
typedef unsigned short v8u16 __attribute__((ext_vector_type(8)));

__device__ __forceinline__ unsigned short bf16rne(float f) {
    unsigned u = __float_as_uint(f);
    return (unsigned short)((u + 0x7fffu + ((u >> 16) & 1u)) >> 16);
}
__device__ __forceinline__ float bf2f(unsigned short h) {
    return __uint_as_float((unsigned)h << 16);
}
__device__ __forceinline__ float fsigmoid(float x) { return 1.0f / (1.0f + __expf(-x)); }
__device__ __forceinline__ float ftanh_(float x) { return 2.0f / (1.0f + __expf(-2.0f * x)) - 1.0f; }

// ---------------- prep: pack weights to bf16 hi/lo ----------------
__global__ void k0_pack(const float* __restrict__ dil_w,
                        const float* __restrict__ res_w,
                        const float* __restrict__ skip_w,
                        unsigned short* __restrict__ WdH, unsigned short* __restrict__ WdL,
                        unsigned short* __restrict__ WrH, unsigned short* __restrict__ WrL,
                        unsigned short* __restrict__ WsH, unsigned short* __restrict__ WsL,
                        int split)
{
    const int Nd = NLAYERS * 1024 * 512;
    const int NWr = NLAYERS * 512 * 512;
    const int NWs = NLAYERS * 256 * 512;
    const int total = Nd + NWr + NWs;
    const int stride = gridDim.x * blockDim.x;
    for (int i = blockIdx.x * blockDim.x + threadIdx.x; i < total; i += stride) {
        if (i < Nd) {
            const int l = i >> 19;
            const int lo19 = i & ((1 << 19) - 1);
            const float* src = dil_w + (size_t)i * 3;
            #pragma unroll
            for (int tap = 0; tap < 3; ++tap) {
                const float w = src[tap];
                const size_t o = ((size_t)(l * 3 + tap) << 19) + lo19;
                const unsigned short h = bf16rne(w);
                WdH[o] = h;
                if (split) WdL[o] = bf16rne(w - bf2f(h));
            }
        } else if (i < Nd + NWr) {
            const int j2 = i - Nd;
            const float w = res_w[j2];
            const unsigned short h = bf16rne(w);
            WrH[j2] = h;
            if (split) WrL[j2] = bf16rne(w - bf2f(h));
        } else {
            const int j2 = i - Nd - NWr;
            const float w = skip_w[j2];
            const unsigned short h = bf16rne(w);
            WsH[j2] = h;
            if (split) WsL[j2] = bf16rne(w - bf2f(h));
        }
    }
}

// ---------------- zero the dilation guard pads of xH/xL --------------------
__global__ __launch_bounds__(256)
void k_zpad(unsigned short* __restrict__ xH, unsigned short* __restrict__ xL)
{
    const int i = blockIdx.x * 256 + threadIdx.x;     // [0, 131072)
    const int row = i >> 6;                           // 2048 pad rows
    const int col = (i & 63) * 8;
    const int b = row >> 10, r = row & 1023;
    const size_t arow = (size_t)b * XSTRIDE + (r < 512 ? r : 8192 + r);
    const size_t o = (arow << 9) + col;
    *(v8u16*)(xH + o) = (v8u16)0;
    *(v8u16*)(xL + o) = (v8u16)0;
}

// ---------------- init: x0 = start_conv(audio) + mel_conv(mel) -------------
__global__ __launch_bounds__(256)
void k_init(const float* __restrict__ audio, const float* __restrict__ mel,
            const float* __restrict__ start_w, const float* __restrict__ start_b,
            const float* __restrict__ mel_w, const float* __restrict__ mel_b,
            unsigned short* __restrict__ xH, unsigned short* __restrict__ xL,
            float* __restrict__ skip_acc, int split)
{
    __shared__ float melw[32 * 84];
    __shared__ float mels[80 * 132];
    const int tid = threadIdx.x;
    const int bid = blockIdx.x;
    const int cc = bid & 15;
    const int tt = (bid >> 4) & 63;
    const int b = bid >> 10;
    const int c0 = cc * 32, t0 = tt * 128;

    for (int i = tid; i < 32 * 80; i += 256) {
        const int c = i / 80, m = i - c * 80;
        melw[c * 84 + m] = mel_w[(size_t)(c0 + c) * MEL_C + m];
    }
    for (int i = tid; i < 80 * 32; i += 256) {
        const int m = i >> 5, t4 = (i & 31) * 4;
        *(float4*)(mels + m * 132 + t4) =
            *(const float4*)(mel + ((size_t)b * MEL_C + m) * TB + t0 + t4);
    }
    __syncthreads();

    const int c = c0 + (tid & 31);
    const int tg = (tid >> 5) * 16;
    float acc[16];
    const float base = start_b[c] + mel_b[c];
    const float sw = start_w[c];
    #pragma unroll
    for (int i = 0; i < 16; ++i)
        acc[i] = fmaf(sw, audio[(size_t)b * TB + t0 + tg + i], base);
    const float* wrow = melw + (tid & 31) * 84;
    for (int m = 0; m < MEL_C; ++m) {
        const float w = wrow[m];
        const float* mr = mels + m * 132 + tg;
        #pragma unroll
        for (int i = 0; i < 16; ++i)
            acc[i] = fmaf(w, mr[i], acc[i]);
    }
    #pragma unroll
    for (int i = 0; i < 16; ++i) {
        const size_t o = ((size_t)(b * XSTRIDE + 512 + t0 + tg + i) << 9) + c;
        const unsigned short h = bf16rne(acc[i]);
        xH[o] = h;
        if (split) xL[o] = bf16rne(acc[i] - bf2f(h));
    }
    if (cc < 8) {
        const int cs = cc * 32 + (tid & 31);
        #pragma unroll
        for (int i = 0; i < 16; ++i)
            skip_acc[(size_t)(b * TB + t0 + tg + i) * SKIP_C + cs] = 0.f;
    }
}

// ---------------- K1: a = tanh(f)*sigmoid(g), f,g = dilated conv -----------
// grid 1024 x 256 thr. mg = bid>>7 (8 m-groups of 64 f-rows), tl = bid&127
// (same-tile blocks are 128 apart -> same XCD). NO LDS, NO barriers:
// both MFMA operands are direct 16B global loads; waves desynchronized.
__global__ __launch_bounds__(256, 3)
void k1_dilgate(const unsigned short* __restrict__ xH,
                const unsigned short* __restrict__ xL,
                unsigned short* __restrict__ aH, unsigned short* __restrict__ aL,
                const unsigned short* __restrict__ WdH,  // [3][1024][512] this layer
                const unsigned short* __restrict__ WdL,
                const float* __restrict__ dil_b,         // [1024] this layer
                int dil, int split)
{
    const int tid = threadIdx.x;
    const int wave = tid >> 6, lane = tid & 63;
    const int quad = lane >> 4, l15 = lane & 15;
    const int mg = blockIdx.x >> 7;
    const int tl = blockIdx.x & 127;
    const int b = tl >> 6;
    const int t0 = (tl & 63) << 7;
    const int frow = mg * 64 + wave * 16 + l15;   // f A-row; g = frow+512

    const v4f vz = {0.f, 0.f, 0.f, 0.f};
    v4f accF[8], accG[8];
    #pragma unroll
    for (int n = 0; n < 8; ++n) { accF[n] = vz; accG[n] = vz; }

    const size_t fo = (size_t)frow * 512;
    const size_t go = (size_t)(frow + 512) * 512;
    const int xbase = b * XSTRIDE + 512 + t0 + l15;

    for (int tap = 0; tap < 3; ++tap) {
        const unsigned short* WH = WdH + ((size_t)tap << 19);
        const unsigned short* WL = WdL + ((size_t)tap << 19);
        const int shift = (tap - 1) * dil;
        unsigned boff[8];
        #pragma unroll
        for (int n = 0; n < 8; ++n)
            boff[n] = (unsigned)(xbase + n * 16 + shift) << 9;
        #pragma unroll 2
        for (int ks = 0; ks < 16; ++ks) {
            const int kg = ks * 32 + quad * 8;
            const v8s afh = *(const v8s*)(WH + fo + kg);
            const v8s agh = *(const v8s*)(WH + go + kg);
            v8s afl, agl;
            if (split) {
                afl = *(const v8s*)(WL + fo + kg);
                agl = *(const v8s*)(WL + go + kg);
            }
            #pragma unroll
            for (int nh = 0; nh < 2; ++nh) {
                v8s bh[4], bl[4];
                #pragma unroll
                for (int j = 0; j < 4; ++j) {
                    bh[j] = *(const v8s*)(xH + boff[nh * 4 + j] + kg);
                    if (split) bl[j] = *(const v8s*)(xL + boff[nh * 4 + j] + kg);
                }
                #pragma unroll
                for (int j = 0; j < 4; ++j) {
                    const int n = nh * 4 + j;
                    accF[n] = __builtin_amdgcn_mfma_f32_16x16x32_bf16(afh, bh[j], accF[n], 0, 0, 0);
                    accG[n] = __builtin_amdgcn_mfma_f32_16x16x32_bf16(agh, bh[j], accG[n], 0, 0, 0);
                    if (split) {
                        accF[n] = __builtin_amdgcn_mfma_f32_16x16x32_bf16(afh, bl[j], accF[n], 0, 0, 0);
                        accF[n] = __builtin_amdgcn_mfma_f32_16x16x32_bf16(afl, bh[j], accF[n], 0, 0, 0);
                        accG[n] = __builtin_amdgcn_mfma_f32_16x16x32_bf16(agh, bl[j], accG[n], 0, 0, 0);
                        accG[n] = __builtin_amdgcn_mfma_f32_16x16x32_bf16(agl, bh[j], accG[n], 0, 0, 0);
                    }
                }
            }
        }
    }
    // gate epilogue: f,g share C-layout (col=t=l15, row=ch=quad*4+reg)
    unsigned short* aHb = aH + (size_t)b * TB * RES_C;
    unsigned short* aLb = aL + (size_t)b * TB * RES_C;
    const int ch = mg * 64 + wave * 16 + quad * 4;
    const float4 bF = *(const float4*)(dil_b + ch);
    const float4 bG = *(const float4*)(dil_b + 512 + ch);
    #pragma unroll
    for (int n = 0; n < 8; ++n) {
        const int t = t0 + n * 16 + l15;
        float a0 = ftanh_(accF[n][0] + bF.x) * fsigmoid(accG[n][0] + bG.x);
        float a1 = ftanh_(accF[n][1] + bF.y) * fsigmoid(accG[n][1] + bG.y);
        float a2 = ftanh_(accF[n][2] + bF.z) * fsigmoid(accG[n][2] + bG.z);
        float a3 = ftanh_(accF[n][3] + bF.w) * fsigmoid(accG[n][3] + bG.w);
        v4u16 oh;
        oh[0] = bf16rne(a0); oh[1] = bf16rne(a1);
        oh[2] = bf16rne(a2); oh[3] = bf16rne(a3);
        *(v4u16*)(aHb + (size_t)t * RES_C + ch) = oh;
        if (split) {
            v4u16 ol;
            ol[0] = bf16rne(a0 - bf2f(oh[0]));
            ol[1] = bf16rne(a1 - bf2f(oh[1]));
            ol[2] = bf16rne(a2 - bf2f(oh[2]));
            ol[3] = bf16rne(a3 - bf2f(oh[3]));
            *(v4u16*)(aLb + (size_t)t * RES_C + ch) = ol;
        }
    }
}

// ---------------- K3: x += res(a); skip += skipconv(a) ---------------------
// Transposed: D[m=t][n=c], A = a[t][k] frags, B = weight rows. No LDS/barriers.
// grid 768 = 256 t-groups(64 t) x 3 block-groups(16 n-tiles); wave = 4m x 4n.
// bg 0,1 -> res rows (c<512), bg 2 -> skip rows. x master = xH+xL (no fp32 x).
__global__ __launch_bounds__(256, 3)
void k3_resskip(unsigned short* __restrict__ xH, unsigned short* __restrict__ xL,
                float* __restrict__ skip_acc,
                const unsigned short* __restrict__ aH,
                const unsigned short* __restrict__ aL,
                const unsigned short* __restrict__ WrH, const unsigned short* __restrict__ WrL,
                const unsigned short* __restrict__ WsH, const unsigned short* __restrict__ WsL,
                const float* __restrict__ res_b, const float* __restrict__ skip_b,
                int split)
{
    const int tid = threadIdx.x;
    const int wave = tid >> 6, lane = tid & 63;
    const int quad = lane >> 4, l15 = lane & 15;
    const int tt = blockIdx.x & 255;
    const int bg = blockIdx.x >> 8;               // 0..2
    const int b = tt >> 7;
    const int t0 = (tt & 127) << 6;
    const int nt0 = bg * 16 + wave * 4;           // first of this wave's 4 n-tiles

    const v4f vz = {0.f, 0.f, 0.f, 0.f};
    v4f acc[4][4];
    #pragma unroll
    for (int mi = 0; mi < 4; ++mi)
        #pragma unroll
        for (int j = 0; j < 4; ++j) acc[mi][j] = vz;

    unsigned aoff[4];
    #pragma unroll
    for (int mi = 0; mi < 4; ++mi)
        aoff[mi] = (unsigned)(b * TB + t0 + mi * 16 + l15) << 9;

    const unsigned short* bHp[4];
    const unsigned short* bLp[4];
    unsigned woff[4];
    #pragma unroll
    for (int j = 0; j < 4; ++j) {
        const int nt = nt0 + j;
        if (nt < 32) {
            bHp[j] = WrH; bLp[j] = WrL;
            woff[j] = (unsigned)(nt * 16 + l15) << 9;
        } else {
            bHp[j] = WsH; bLp[j] = WsL;
            woff[j] = (unsigned)((nt - 32) * 16 + l15) << 9;
        }
    }

    #pragma unroll 2
    for (int kc = 0; kc < 16; ++kc) {
        const int kg = kc * 32 + quad * 8;
        v8s ah[4], al[4];
        #pragma unroll
        for (int mi = 0; mi < 4; ++mi) {
            ah[mi] = *(const v8s*)(aH + aoff[mi] + kg);
            if (split) al[mi] = *(const v8s*)(aL + aoff[mi] + kg);
        }
        #pragma unroll
        for (int j = 0; j < 4; ++j) {
            const v8s bh = *(const v8s*)(bHp[j] + woff[j] + kg);
            v8s bl;
            if (split) bl = *(const v8s*)(bLp[j] + woff[j] + kg);
            #pragma unroll
            for (int mi = 0; mi < 4; ++mi) {
                acc[mi][j] = __builtin_amdgcn_mfma_f32_16x16x32_bf16(ah[mi], bh, acc[mi][j], 0, 0, 0);
                if (split) {
                    acc[mi][j] = __builtin_amdgcn_mfma_f32_16x16x32_bf16(ah[mi], bl, acc[mi][j], 0, 0, 0);
                    acc[mi][j] = __builtin_amdgcn_mfma_f32_16x16x32_bf16(al[mi], bh, acc[mi][j], 0, 0, 0);
                }
            }
        }
    }

    // epilogue: col=c=l15, row=t=quad*4+reg
    #pragma unroll
    for (int j = 0; j < 4; ++j) {
        const int nt = nt0 + j;
        if (nt < 32) {
            const int c = nt * 16 + l15;
            const float bias = res_b[c];
            #pragma unroll
            for (int mi = 0; mi < 4; ++mi) {
                #pragma unroll
                for (int r = 0; r < 4; ++r) {
                    const int t = t0 + mi * 16 + quad * 4 + r;
                    const size_t op = ((size_t)(b * XSTRIDE + 512 + t) << 9) + c;
                    float xv = bf2f(xH[op]);
                    if (split) xv += bf2f(xL[op]);
                    const float v = xv + acc[mi][j][r] + bias;
                    const unsigned short h = bf16rne(v);
                    xH[op] = h;
                    if (split) xL[op] = bf16rne(v - bf2f(h));
                }
            }
        } else {
            const int c2 = (nt - 32) * 16 + l15;
            const float bias = skip_b[c2];
            #pragma unroll
            for (int mi = 0; mi < 4; ++mi) {
                #pragma unroll
                for (int r = 0; r < 4; ++r) {
                    const int t = t0 + mi * 16 + quad * 4 + r;
                    const size_t o = (size_t)(b * TB + t) * SKIP_C + c2;
                    skip_acc[o] += acc[mi][j][r] + bias;
                }
            }
        }
    }
}

// ---------------- final: out = tanh(fc2(relu(fc1(skip)))) ------------------
__global__ __launch_bounds__(256)
void k4_final(const float* __restrict__ skip_acc,
              const float* __restrict__ fc1_w, const float* __restrict__ fc1_b,
              const float* __restrict__ fc2_w, const float* __restrict__ fc2_b,
              float* __restrict__ out)
{
    __shared__ float stile[32 * 260];
    __shared__ float part[8][32];
    const int tid = threadIdx.x;
    const int b = blockIdx.x >> 8;
    const int t0 = (blockIdx.x & 255) << 5;
    {
        const int r = tid >> 3, sub = tid & 7;
        const float* srow = skip_acc + (size_t)(b * TB + t0 + r) * SKIP_C;
        float* drow = stile + r * 260;
        #pragma unroll
        for (int i = 0; i < 8; ++i) {
            const int c = (i * 8 + sub) * 4;
            *(float4*)(drow + c) = *(const float4*)(srow + c);
        }
    }
    __syncthreads();
    const int t = tid & 31;
    const int w = tid >> 5;
    float y[32];
    #pragma unroll
    for (int co = 0; co < 32; ++co) y[co] = fc1_b[w * 32 + co];
    const float* srow = stile + t * 260;
    for (int ci = 0; ci < SKIP_C; ++ci) {
        const float s = srow[ci];
        const float* wcol = fc1_w + (size_t)(w * 32) * SKIP_C + ci;
        #pragma unroll
        for (int co = 0; co < 32; ++co)
            y[co] = fmaf(wcol[(size_t)co * SKIP_C], s, y[co]);
    }
    float partial = 0.f;
    #pragma unroll
    for (int co = 0; co < 32; ++co) {
        const float v = y[co] > 0.f ? y[co] : 0.f;
        partial = fmaf(fc2_w[w * 32 + co], v, partial);
    }
    part[w][t] = partial;
    __syncthreads();
    if (tid < 32) {
        float v = fc2_b[0];
        #pragma unroll
        for (int k = 0; k < 8; ++k) v += part[k][tid];
        out[(size_t)b * TB + t0 + tid] = ftanh_(v);
    }
}

// ---------------- host ----------------
extern "C" void kernel_launch(void* const* d_in, const int* in_sizes, int n_in,
                              void* d_out, int out_size, void* d_ws, size_t ws_size,
                              hipStream_t stream)
{
    const float* mel     = (const float*)d_in[0];
    const float* audio   = (const float*)d_in[1];
    const float* start_w = (const float*)d_in[2];
    const float* start_b = (const float*)d_in[3];
    const float* mel_w   = (const float*)d_in[4];
    const float* mel_b   = (const float*)d_in[5];
    const float* dil_b   = (const float*)d_in[7];
    const float* res_b   = (const float*)d_in[9];
    const float* skip_b  = (const float*)d_in[11];
    const float* fc1_w   = (const float*)d_in[12];
    const float* fc1_b   = (const float*)d_in[13];
    const float* fc2_w   = (const float*)d_in[14];
    const float* fc2_b   = (const float*)d_in[15];
    float* out = (float*)d_out;

    char* ws = (char*)d_ws;
    const size_t szWd  = (size_t)NLAYERS * 3 * 1024 * 512 * 2;     // 94.4 MB
    const size_t szWr  = (size_t)NLAYERS * 512 * 512 * 2;          // 15.7 MB
    const size_t szWs  = (size_t)NLAYERS * 256 * 512 * 2;          //  7.9 MB
    const size_t szXp  = (size_t)NBATCH * XSTRIDE * RES_C * 2;     // 18.9 MB (padded)
    const size_t szA16 = (size_t)NBATCH * TB * RES_C * 2;          // 16.8 MB
    const size_t szSk  = (size_t)NBATCH * TB * SKIP_C * 4;         // 16.8 MB
    size_t off = 0;
    unsigned short* WdH = (unsigned short*)(ws + off); off += szWd;
    unsigned short* WrH = (unsigned short*)(ws + off); off += szWr;
    unsigned short* WsH = (unsigned short*)(ws + off); off += szWs;
    unsigned short* xH  = (unsigned short*)(ws + off); off += szXp;
    unsigned short* aH  = (unsigned short*)(ws + off); off += szA16;
    float* skip_acc     = (float*)(ws + off);          off += szSk;
    const size_t lo_need = szXp + szA16 + szWd + szWr + szWs;
    const int split = (off + lo_need <= ws_size) ? 1 : 0;
    unsigned short* xL  = split ? (unsigned short*)(ws + off) : xH; if (split) off += szXp;
    unsigned short* aL  = split ? (unsigned short*)(ws + off) : aH; if (split) off += szA16;
    unsigned short* WdL = split ? (unsigned short*)(ws + off) : WdH; if (split) off += szWd;
    unsigned short* WrL = split ? (unsigned short*)(ws + off) : WrH; if (split) off += szWr;
    unsigned short* WsL = split ? (unsigned short*)(ws + off) : WsH; if (split) off += szWs;

    k0_pack<<<8192, 256, 0, stream>>>((const float*)d_in[6], (const float*)d_in[8],
                                      (const float*)d_in[10],
                                      WdH, WdL, WrH, WrL, WsH, WsL, split);
    k_zpad<<<512, 256, 0, stream>>>(xH, xL);
    k_init<<<2048, 256, 0, stream>>>(
        audio, mel, start_w, start_b, mel_w, mel_b, xH, xL, skip_acc, split);

    for (int l = 0; l < NLAYERS; ++l) {
        const int dil = 1 << (l % 10);
        k1_dilgate<<<1024, 256, 0, stream>>>(xH, xL, aH, aL,
            WdH + (size_t)l * 3 * 1024 * 512, WdL + (size_t)l * 3 * 1024 * 512,
            dil_b + (size_t)l * 1024, dil, split);
        k3_resskip<<<768, 256, 0, stream>>>(xH, xL, skip_acc, aH, aL,
            WrH + (size_t)l * 512 * 512, WrL + (size_t)l * 512 * 512,
            WsH + (size_t)l * 256 * 512, WsL + (size_t)l * 256 * 512,
            res_b + (size_t)l * 512, skip_b + (size_t)l * 256, split);
    }
    k4_final<<<512, 256, 0, stream>>>(skip_acc, fc1_w, fc1_b, fc2_w, fc2_b, out);
}

// Round 6
// 9104.433 us; speedup vs baseline: 2.2992x; 2.2992x over previous
//
#include <hip/hip_runtime.h>
#include <stdint.h>

#define TB 8192
#define NBATCH 2
#define RES_C 512
#define SKIP_C 256
#define MEL_C 80
#define NLAYERS 30
#define XSTRIDE 9216   // TB + 2*512 zero-pad rows per batch (dilation guard)

typedef short v8s __attribute__((ext_vector_type(8)));
typedef float v4f __attribute__((ext_vector_type(4)));
typedef unsigned short v4u16 __attribute__((ext_vector_type(4)));
typedef unsigned short v8u16 __attribute__((ext_vector_type(8)));

__device__ __forceinline__ unsigned short bf16rne(float f) {
    unsigned u = __float_as_uint(f);
    return (unsigned short)((u + 0x7fffu + ((u >> 16) & 1u)) >> 16);
}
__device__ __forceinline__ float bf2f(unsigned short h) {
    return __uint_as_float((unsigned)h << 16);
}
__device__ __forceinline__ float fsigmoid(float x) { return 1.0f / (1.0f + __expf(-x)); }
__device__ __forceinline__ float ftanh_(float x) { return 2.0f / (1.0f + __expf(-2.0f * x)) - 1.0f; }

// Fragment-packed index: tile rt=row>>4, ks=k>>5 -> 1KB block of [lane 64][8]
__device__ __forceinline__ size_t fragpos(int row, int k, int ntile16) {
    return ((size_t)((row >> 4) * 16 + (k >> 5)) << 9)
         + (((k & 31) >> 3) << 7) + ((row & 15) << 3) + (k & 7);
    (void)ntile16;
}

// ---------------- prep: pack weights to bf16 hi/lo, FRAGMENT order --------
__global__ void k0_pack(const float* __restrict__ dil_w,
                        const float* __restrict__ res_w,
                        const float* __restrict__ skip_w,
                        unsigned short* __restrict__ WdH, unsigned short* __restrict__ WdL,
                        unsigned short* __restrict__ WrH, unsigned short* __restrict__ WrL,
                        unsigned short* __restrict__ WsH, unsigned short* __restrict__ WsL,
                        int split)
{
    const int Nd = NLAYERS * 1024 * 512;
    const int NWr = NLAYERS * 512 * 512;
    const int NWs = NLAYERS * 256 * 512;
    const int total = Nd + NWr + NWs;
    const int stride = gridDim.x * blockDim.x;
    for (int i = blockIdx.x * blockDim.x + threadIdx.x; i < total; i += stride) {
        if (i < Nd) {
            const int l = i >> 19;
            const int rest = i & ((1 << 19) - 1);
            const int row = rest >> 9, ci = rest & 511;
            const size_t sub = (((size_t)((ci & 31) >> 3)) << 7) + ((row & 15) << 3) + (ci & 7);
            const float* src = dil_w + (size_t)i * 3;
            #pragma unroll
            for (int tap = 0; tap < 3; ++tap) {
                const float w = src[tap];
                // dst: [l][ (tap*64 + row>>4)*16 + ci>>5 ][lane][8]
                const size_t o = (size_t)l * 1572864
                               + ((size_t)((tap * 64 + (row >> 4)) * 16 + (ci >> 5)) << 9) + sub;
                const unsigned short h = bf16rne(w);
                WdH[o] = h;
                if (split) WdL[o] = bf16rne(w - bf2f(h));
            }
        } else if (i < Nd + NWr) {
            const int j = i - Nd;
            const int l = j >> 18;
            const int rest = j & ((1 << 18) - 1);
            const int row = rest >> 9, ci = rest & 511;
            const size_t o = (size_t)l * 262144 + fragpos(row, ci, 0);
            const float w = res_w[j];
            const unsigned short h = bf16rne(w);
            WrH[o] = h;
            if (split) WrL[o] = bf16rne(w - bf2f(h));
        } else {
            const int j = i - Nd - NWr;
            const int l = j >> 17;
            const int rest = j & ((1 << 17) - 1);
            const int row = rest >> 9, ci = rest & 511;
            const size_t o = (size_t)l * 131072 + fragpos(row, ci, 0);
            const float w = skip_w[j];
            const unsigned short h = bf16rne(w);
            WsH[o] = h;
            if (split) WsL[o] = bf16rne(w - bf2f(h));
        }
    }
}

// ---------------- zero the dilation guard pads of xH/xL --------------------
__global__ __launch_bounds__(256)
void k_zpad(unsigned short* __restrict__ xH, unsigned short* __restrict__ xL)
{
    const int i = blockIdx.x * 256 + threadIdx.x;     // [0, 131072)
    const int row = i >> 6;                           // 2048 pad rows
    const int col = (i & 63) * 8;
    const int b = row >> 10, r = row & 1023;
    const size_t arow = (size_t)b * XSTRIDE + (r < 512 ? r : 8192 + r);
    const size_t o = (arow << 9) + col;
    *(v8u16*)(xH + o) = (v8u16)0;
    *(v8u16*)(xL + o) = (v8u16)0;
}

// ---------------- init: x0 = start_conv(audio) + mel_conv(mel) -------------
__global__ __launch_bounds__(256)
void k_init(const float* __restrict__ audio, const float* __restrict__ mel,
            const float* __restrict__ start_w, const float* __restrict__ start_b,
            const float* __restrict__ mel_w, const float* __restrict__ mel_b,
            unsigned short* __restrict__ xH, unsigned short* __restrict__ xL,
            float* __restrict__ skip_acc, int split)
{
    __shared__ float melw[32 * 84];
    __shared__ float mels[80 * 132];
    const int tid = threadIdx.x;
    const int bid = blockIdx.x;
    const int cc = bid & 15;
    const int tt = (bid >> 4) & 63;
    const int b = bid >> 10;
    const int c0 = cc * 32, t0 = tt * 128;

    for (int i = tid; i < 32 * 80; i += 256) {
        const int c = i / 80, m = i - c * 80;
        melw[c * 84 + m] = mel_w[(size_t)(c0 + c) * MEL_C + m];
    }
    for (int i = tid; i < 80 * 32; i += 256) {
        const int m = i >> 5, t4 = (i & 31) * 4;
        *(float4*)(mels + m * 132 + t4) =
            *(const float4*)(mel + ((size_t)b * MEL_C + m) * TB + t0 + t4);
    }
    __syncthreads();

    const int c = c0 + (tid & 31);
    const int tg = (tid >> 5) * 16;
    float acc[16];
    const float base = start_b[c] + mel_b[c];
    const float sw = start_w[c];
    #pragma unroll
    for (int i = 0; i < 16; ++i)
        acc[i] = fmaf(sw, audio[(size_t)b * TB + t0 + tg + i], base);
    const float* wrow = melw + (tid & 31) * 84;
    for (int m = 0; m < MEL_C; ++m) {
        const float w = wrow[m];
        const float* mr = mels + m * 132 + tg;
        #pragma unroll
        for (int i = 0; i < 16; ++i)
            acc[i] = fmaf(w, mr[i], acc[i]);
    }
    #pragma unroll
    for (int i = 0; i < 16; ++i) {
        const size_t o = ((size_t)(b * XSTRIDE + 512 + t0 + tg + i) << 9) + c;
        const unsigned short h = bf16rne(acc[i]);
        xH[o] = h;
        if (split) xL[o] = bf16rne(acc[i] - bf2f(h));
    }
    if (cc < 8) {
        const int cs = cc * 32 + (tid & 31);
        #pragma unroll
        for (int i = 0; i < 16; ++i)
            skip_acc[(size_t)(b * TB + t0 + tg + i) * SKIP_C + cs] = 0.f;
    }
}

// ---------------- K1: a = tanh(f)*sigmoid(g), f,g = dilated conv -----------
// grid 1024 = 8 p-eighths (bid&7 -> XCD-pinned, weight slice 768KB L2-resident)
//           x 128 t-tiles of 128. 256 thr = 4 waves; wave w: f-rows p*64+w*16..+15.
// LDS: x K-chunk 32, double-buffered (32KB) -> 4 blocks/CU, barrier-decoupled.
// Weights fragment-packed -> A-loads are single coalesced 1KB wave-loads.
// Output a written in k3's A-fragment layout (free in epilogue).
__global__ __launch_bounds__(256, 4)
void k1_dilgate(const unsigned short* __restrict__ xH,
                const unsigned short* __restrict__ xL,
                unsigned short* __restrict__ aH, unsigned short* __restrict__ aL,
                const unsigned short* __restrict__ WdH,  // packed, this layer
                const unsigned short* __restrict__ WdL,
                const float* __restrict__ dil_b,         // [1024] this layer
                int dil, int split)
{
    __shared__ unsigned short shi[2][128 * 32];
    __shared__ unsigned short slo[2][128 * 32];
    const int tid = threadIdx.x;
    const int wave = tid >> 6, lane = tid & 63;
    const int quad = lane >> 4, l15 = lane & 15;
    const int p = blockIdx.x & 7;
    const int tl = blockIdx.x >> 3;           // 0..127
    const int b = tl >> 6;
    const int t0 = (tl & 63) << 7;
    const int chbase = p * 64 + wave * 16;    // f-row tile base
    const int rtf = chbase >> 4;              // f tile (0..31); g tile = +32

    const v4f vz = {0.f, 0.f, 0.f, 0.f};
    v4f accF[8], accG[8];
    #pragma unroll
    for (int n = 0; n < 8; ++n) { accF[n] = vz; accG[n] = vz; }

    const int sr = tid >> 1, half = tid & 1;  // staging: 128 rows x 2 threads
    v8u16 rH[2], rL[2];

    auto do_load = [&](int ph) {
        const int tap = ph >> 4, ks = ph & 15;
        const int tsrc = t0 + sr + (tap - 1) * dil;     // guards zero-padded
        const size_t rowo = ((size_t)(b * XSTRIDE + 512 + tsrc) << 9) + ks * 32 + half * 16;
        rH[0] = *(const v8u16*)(xH + rowo);
        rH[1] = *(const v8u16*)(xH + rowo + 8);
        if (split) {
            rL[0] = *(const v8u16*)(xL + rowo);
            rL[1] = *(const v8u16*)(xL + rowo + 8);
        }
    };

    do_load(0);
    for (int ph = 0; ph < 48; ++ph) {
        const int buf = ph & 1;
        __syncthreads();
        {
            const int c0 = half * 2;
            unsigned short* dh = &shi[buf][sr * 32];
            unsigned short* dl = &slo[buf][sr * 32];
            *(v8u16*)(dh + (((c0    ) ^ (sr & 3)) << 3)) = rH[0];
            *(v8u16*)(dh + (((c0 + 1) ^ (sr & 3)) << 3)) = rH[1];
            if (split) {
                *(v8u16*)(dl + (((c0    ) ^ (sr & 3)) << 3)) = rL[0];
                *(v8u16*)(dl + (((c0 + 1) ^ (sr & 3)) << 3)) = rL[1];
            }
        }
        __syncthreads();
        if (ph < 47) do_load(ph + 1);         // in flight during compute

        const int tap = ph >> 4, ks = ph & 15;
        const size_t wfo = ((size_t)((tap * 64 + rtf) * 16 + ks) << 9) + lane * 8;
        const size_t wgo = ((size_t)((tap * 64 + rtf + 32) * 16 + ks) << 9) + lane * 8;
        const v8s afh = *(const v8s*)(WdH + wfo);
        const v8s agh = *(const v8s*)(WdH + wgo);
        v8s afl, agl;
        if (split) {
            afl = *(const v8s*)(WdL + wfo);
            agl = *(const v8s*)(WdL + wgo);
        }
        #pragma unroll
        for (int jg = 0; jg < 4; ++jg) {
            v8s bh[2], bl[2];
            #pragma unroll
            for (int j2 = 0; j2 < 2; ++j2) {
                const int trow = (jg * 2 + j2) * 16 + l15;
                const int pos = trow * 32 + ((quad ^ (trow & 3)) << 3);
                bh[j2] = *(const v8s*)(&shi[buf][pos]);
                if (split) bl[j2] = *(const v8s*)(&slo[buf][pos]);
            }
            #pragma unroll
            for (int j2 = 0; j2 < 2; ++j2) {
                const int n = jg * 2 + j2;
                accF[n] = __builtin_amdgcn_mfma_f32_16x16x32_bf16(afh, bh[j2], accF[n], 0, 0, 0);
                accG[n] = __builtin_amdgcn_mfma_f32_16x16x32_bf16(agh, bh[j2], accG[n], 0, 0, 0);
                if (split) {
                    accF[n] = __builtin_amdgcn_mfma_f32_16x16x32_bf16(afh, bl[j2], accF[n], 0, 0, 0);
                    accF[n] = __builtin_amdgcn_mfma_f32_16x16x32_bf16(afl, bh[j2], accF[n], 0, 0, 0);
                    accG[n] = __builtin_amdgcn_mfma_f32_16x16x32_bf16(agh, bl[j2], accG[n], 0, 0, 0);
                    accG[n] = __builtin_amdgcn_mfma_f32_16x16x32_bf16(agl, bh[j2], accG[n], 0, 0, 0);
                }
            }
        }
    }
    // gate epilogue; write a in k3 A-frag layout:
    // pos = b*TB*512 + (t>>4)*8192 + (ch>>5)*512 + chunk*128 + (t&15)*8 + (quad&1)*4
    const int chq = chbase + quad * 4;
    const int kc = chbase >> 5;
    const int chunk = ((chbase >> 4) & 1) * 2 + (quad >> 1);
    const int q1 = quad & 1;
    const float4 bF = *(const float4*)(dil_b + chq);
    const float4 bG = *(const float4*)(dil_b + 512 + chq);
    const size_t abase = (size_t)b * TB * 512 + (size_t)kc * 512
                       + (size_t)chunk * 128 + l15 * 8 + q1 * 4;
    #pragma unroll
    for (int n = 0; n < 8; ++n) {
        float a0 = ftanh_(accF[n][0] + bF.x) * fsigmoid(accG[n][0] + bG.x);
        float a1 = ftanh_(accF[n][1] + bF.y) * fsigmoid(accG[n][1] + bG.y);
        float a2 = ftanh_(accF[n][2] + bF.z) * fsigmoid(accG[n][2] + bG.z);
        float a3 = ftanh_(accF[n][3] + bF.w) * fsigmoid(accG[n][3] + bG.w);
        const size_t pos = abase + (size_t)((t0 >> 4) + n) * 8192;
        v4u16 oh;
        oh[0] = bf16rne(a0); oh[1] = bf16rne(a1);
        oh[2] = bf16rne(a2); oh[3] = bf16rne(a3);
        *(v4u16*)(aH + pos) = oh;
        if (split) {
            v4u16 ol;
            ol[0] = bf16rne(a0 - bf2f(oh[0]));
            ol[1] = bf16rne(a1 - bf2f(oh[1]));
            ol[2] = bf16rne(a2 - bf2f(oh[2]));
            ol[3] = bf16rne(a3 - bf2f(oh[3]));
            *(v4u16*)(aL + pos) = ol;
        }
    }
}

// ---------------- K3: x += res(a); skip += skipconv(a) ---------------------
// Barrier-free (R5-proven fast). All operands fragment-packed & coalesced.
// grid 768 = 256 t-groups(64 t) x 3 block-groups; wave = 4m x 4n tiles.
__global__ __launch_bounds__(256, 4)
void k3_resskip(unsigned short* __restrict__ xH, unsigned short* __restrict__ xL,
                float* __restrict__ skip_acc,
                const unsigned short* __restrict__ aH,
                const unsigned short* __restrict__ aL,
                const unsigned short* __restrict__ WrH, const unsigned short* __restrict__ WrL,
                const unsigned short* __restrict__ WsH, const unsigned short* __restrict__ WsL,
                const float* __restrict__ res_b, const float* __restrict__ skip_b,
                int split)
{
    const int tid = threadIdx.x;
    const int wave = tid >> 6, lane = tid & 63;
    const int quad = lane >> 4, l15 = lane & 15;
    const int tt = blockIdx.x & 255;
    const int bg = blockIdx.x >> 8;               // 0..2
    const int b = tt >> 7;
    const int t0 = (tt & 127) << 6;
    const int nt0 = bg * 16 + wave * 4;           // 4 n-tiles; res nt<32, skip >=32

    const v4f vz = {0.f, 0.f, 0.f, 0.f};
    v4f acc[4][4];
    #pragma unroll
    for (int mi = 0; mi < 4; ++mi)
        #pragma unroll
        for (int j = 0; j < 4; ++j) acc[mi][j] = vz;

    const size_t ab = (size_t)b * TB * 512 + lane * 8;
    const unsigned short* bHp[4];
    const unsigned short* bLp[4];
    unsigned wt[4];
    #pragma unroll
    for (int j = 0; j < 4; ++j) {
        const int nt = nt0 + j;
        if (nt < 32) { bHp[j] = WrH; bLp[j] = WrL; wt[j] = nt; }
        else         { bHp[j] = WsH; bLp[j] = WsL; wt[j] = nt - 32; }
    }

    for (int kc = 0; kc < 16; ++kc) {
        v8s ah[4], al[4];
        #pragma unroll
        for (int mi = 0; mi < 4; ++mi) {
            const size_t pos = ab + (size_t)((t0 >> 4) + mi) * 8192 + kc * 512;
            ah[mi] = *(const v8s*)(aH + pos);
            if (split) al[mi] = *(const v8s*)(aL + pos);
        }
        #pragma unroll
        for (int j = 0; j < 4; ++j) {
            const size_t wpos = ((size_t)(wt[j] * 16 + kc) << 9) + lane * 8;
            const v8s bh = *(const v8s*)(bHp[j] + wpos);
            v8s bl;
            if (split) bl = *(const v8s*)(bLp[j] + wpos);
            #pragma unroll
            for (int mi = 0; mi < 4; ++mi) {
                acc[mi][j] = __builtin_amdgcn_mfma_f32_16x16x32_bf16(ah[mi], bh, acc[mi][j], 0, 0, 0);
                if (split) {
                    acc[mi][j] = __builtin_amdgcn_mfma_f32_16x16x32_bf16(ah[mi], bl, acc[mi][j], 0, 0, 0);
                    acc[mi][j] = __builtin_amdgcn_mfma_f32_16x16x32_bf16(al[mi], bh, acc[mi][j], 0, 0, 0);
                }
            }
        }
    }

    // epilogue: col(N)=c=l15-based, row(M)=t=quad*4+r
    #pragma unroll
    for (int j = 0; j < 4; ++j) {
        const int nt = nt0 + j;
        if (nt < 32) {
            const int c = nt * 16 + l15;
            const float bias = res_b[c];
            #pragma unroll
            for (int mi = 0; mi < 4; ++mi) {
                #pragma unroll
                for (int r = 0; r < 4; ++r) {
                    const int t = t0 + mi * 16 + quad * 4 + r;
                    const size_t op = ((size_t)(b * XSTRIDE + 512 + t) << 9) + c;
                    float xv = bf2f(xH[op]);
                    if (split) xv += bf2f(xL[op]);
                    const float v = xv + acc[mi][j][r] + bias;
                    const unsigned short h = bf16rne(v);
                    xH[op] = h;
                    if (split) xL[op] = bf16rne(v - bf2f(h));
                }
            }
        } else {
            const int c2 = (nt - 32) * 16 + l15;
            const float bias = skip_b[c2];
            #pragma unroll
            for (int mi = 0; mi < 4; ++mi) {
                #pragma unroll
                for (int r = 0; r < 4; ++r) {
                    const int t = t0 + mi * 16 + quad * 4 + r;
                    const size_t o = (size_t)(b * TB + t) * SKIP_C + c2;
                    skip_acc[o] += acc[mi][j][r] + bias;
                }
            }
        }
    }
}

// ---------------- final: out = tanh(fc2(relu(fc1(skip)))) ------------------
__global__ __launch_bounds__(256)
void k4_final(const float* __restrict__ skip_acc,
              const float* __restrict__ fc1_w, const float* __restrict__ fc1_b,
              const float* __restrict__ fc2_w, const float* __restrict__ fc2_b,
              float* __restrict__ out)
{
    __shared__ float stile[32 * 260];
    __shared__ float part[8][32];
    const int tid = threadIdx.x;
    const int b = blockIdx.x >> 8;
    const int t0 = (blockIdx.x & 255) << 5;
    {
        const int r = tid >> 3, sub = tid & 7;
        const float* srow = skip_acc + (size_t)(b * TB + t0 + r) * SKIP_C;
        float* drow = stile + r * 260;
        #pragma unroll
        for (int i = 0; i < 8; ++i) {
            const int c = (i * 8 + sub) * 4;
            *(float4*)(drow + c) = *(const float4*)(srow + c);
        }
    }
    __syncthreads();
    const int t = tid & 31;
    const int w = tid >> 5;
    float y[32];
    #pragma unroll
    for (int co = 0; co < 32; ++co) y[co] = fc1_b[w * 32 + co];
    const float* srow = stile + t * 260;
    for (int ci = 0; ci < SKIP_C; ++ci) {
        const float s = srow[ci];
        const float* wcol = fc1_w + (size_t)(w * 32) * SKIP_C + ci;
        #pragma unroll
        for (int co = 0; co < 32; ++co)
            y[co] = fmaf(wcol[(size_t)co * SKIP_C], s, y[co]);
    }
    float partial = 0.f;
    #pragma unroll
    for (int co = 0; co < 32; ++co) {
        const float v = y[co] > 0.f ? y[co] : 0.f;
        partial = fmaf(fc2_w[w * 32 + co], v, partial);
    }
    part[w][t] = partial;
    __syncthreads();
    if (tid < 32) {
        float v = fc2_b[0];
        #pragma unroll
        for (int k = 0; k < 8; ++k) v += part[k][tid];
        out[(size_t)b * TB + t0 + tid] = ftanh_(v);
    }
}

// ---------------- host ----------------
extern "C" void kernel_launch(void* const* d_in, const int* in_sizes, int n_in,
                              void* d_out, int out_size, void* d_ws, size_t ws_size,
                              hipStream_t stream)
{
    const float* mel     = (const float*)d_in[0];
    const float* audio   = (const float*)d_in[1];
    const float* start_w = (const float*)d_in[2];
    const float* start_b = (const float*)d_in[3];
    const float* mel_w   = (const float*)d_in[4];
    const float* mel_b   = (const float*)d_in[5];
    const float* dil_b   = (const float*)d_in[7];
    const float* res_b   = (const float*)d_in[9];
    const float* skip_b  = (const float*)d_in[11];
    const float* fc1_w   = (const float*)d_in[12];
    const float* fc1_b   = (const float*)d_in[13];
    const float* fc2_w   = (const float*)d_in[14];
    const float* fc2_b   = (const float*)d_in[15];
    float* out = (float*)d_out;

    char* ws = (char*)d_ws;
    const size_t szWd  = (size_t)NLAYERS * 3 * 1024 * 512 * 2;     // 94.4 MB
    const size_t szWr  = (size_t)NLAYERS * 512 * 512 * 2;          // 15.7 MB
    const size_t szWs  = (size_t)NLAYERS * 256 * 512 * 2;          //  7.9 MB
    const size_t szXp  = (size_t)NBATCH * XSTRIDE * RES_C * 2;     // 18.9 MB (padded)
    const size_t szA16 = (size_t)NBATCH * TB * RES_C * 2;          // 16.8 MB
    const size_t szSk  = (size_t)NBATCH * TB * SKIP_C * 4;         // 16.8 MB
    size_t off = 0;
    unsigned short* WdH = (unsigned short*)(ws + off); off += szWd;
    unsigned short* WrH = (unsigned short*)(ws + off); off += szWr;
    unsigned short* WsH = (unsigned short*)(ws + off); off += szWs;
    unsigned short* xH  = (unsigned short*)(ws + off); off += szXp;
    unsigned short* aH  = (unsigned short*)(ws + off); off += szA16;
    float* skip_acc     = (float*)(ws + off);          off += szSk;
    const size_t lo_need = szXp + szA16 + szWd + szWr + szWs;
    const int split = (off + lo_need <= ws_size) ? 1 : 0;
    unsigned short* xL  = split ? (unsigned short*)(ws + off) : xH; if (split) off += szXp;
    unsigned short* aL  = split ? (unsigned short*)(ws + off) : aH; if (split) off += szA16;
    unsigned short* WdL = split ? (unsigned short*)(ws + off) : WdH; if (split) off += szWd;
    unsigned short* WrL = split ? (unsigned short*)(ws + off) : WrH; if (split) off += szWr;
    unsigned short* WsL = split ? (unsigned short*)(ws + off) : WsH; if (split) off += szWs;

    k0_pack<<<8192, 256, 0, stream>>>((const float*)d_in[6], (const float*)d_in[8],
                                      (const float*)d_in[10],
                                      WdH, WdL, WrH, WrL, WsH, WsL, split);
    k_zpad<<<512, 256, 0, stream>>>(xH, xL);
    k_init<<<2048, 256, 0, stream>>>(
        audio, mel, start_w, start_b, mel_w, mel_b, xH, xL, skip_acc, split);

    for (int l = 0; l < NLAYERS; ++l) {
        const int dil = 1 << (l % 10);
        k1_dilgate<<<1024, 256, 0, stream>>>(xH, xL, aH, aL,
            WdH + (size_t)l * 1572864, WdL + (size_t)l * 1572864,
            dil_b + (size_t)l * 1024, dil, split);
        k3_resskip<<<768, 256, 0, stream>>>(xH, xL, skip_acc, aH, aL,
            WrH + (size_t)l * 262144, WrL + (size_t)l * 262144,
            WsH + (size_t)l * 131072, WsL + (size_t)l * 131072,
            res_b + (size_t)l * 512, skip_b + (size_t)l * 256, split);
    }
    k4_final<<<512, 256, 0, stream>>>(skip_acc, fc1_w, fc1_b, fc2_w, fc2_b, out);
}